// Round 1
// baseline (2832.481 us; speedup 1.0000x reference)
//
#include <hip/hip_runtime.h>
#include <cstdint>
#include <cstddef>

// Problem constants
#define BB_ 16
#define HH_ 64
#define WW_ 64
#define CC_ 256
#define WD_ 127
#define RPD 1024   // rows per direction (B*H)
#define RT_ 2048   // total rows (both directions stacked)

typedef float  f32x4 __attribute__((ext_vector_type(4)));
typedef short  s16x8 __attribute__((ext_vector_type(8)));

__device__ __forceinline__ unsigned short f2bf(float f) {
  unsigned u = __float_as_uint(f);
  u += 0x7fffu + ((u >> 16) & 1u);   // round-to-nearest-even
  return (unsigned short)(u >> 16);
}
__device__ __forceinline__ float bf2f(unsigned short h) {
  return __uint_as_float(((unsigned)h) << 16);
}

// ---------------------------------------------------------------------------
// prep: build masked i2s weights (fp32), bf16 B-operand-layout weight packs,
// and fused bias vectors. Gate-interleaved order: n = chb*64 + g*16 + cl,
// channel ch = chb*16 + cl, original gate row j = g*256 + ch.
// ---------------------------------------------------------------------------
__global__ __launch_bounds__(256) void prep_kernel(
    const float* __restrict__ w_i2s, const float* __restrict__ b_i2s,
    const float* __restrict__ w_ih,  const float* __restrict__ b_ih,
    const float* __restrict__ b_hh,  const float* __restrict__ k0,
    const float* __restrict__ k1,    const float* __restrict__ b_s2s,
    float* __restrict__ wm, unsigned short* __restrict__ K01,
    unsigned short* __restrict__ W2T, float* __restrict__ cvec,
    float* __restrict__ gbias) {
  int idx = blockIdx.x * 256 + threadIdx.x;
  if (idx < 65536) {                       // wm[c][cin], masked
    int c = idx >> 8, ci = idx & 255;
    wm[idx] = ((ci % 3) <= (c % 3)) ? w_i2s[idx] : 0.0f;
  }
  int i2 = idx - 65536;                    // K01[n][k], k<256->k0 row n, else k1
  if (i2 >= 0 && i2 < 131072) {
    int n = i2 >> 9, k = i2 & 511;
    float v = (k < 256) ? k0[n * 256 + k] : k1[n * 256 + (k - 256)];
    K01[i2] = f2bf(v);
  }
  int i3 = idx - 196608;                   // W2T[n][k] = w_ih[j(n)][k]
  if (i3 >= 0 && i3 < 262144) {
    int n = i3 >> 8, k = i3 & 255;
    int chb = n >> 6, g = (n >> 4) & 3, cl = n & 15;
    int j = g * 256 + chb * 16 + cl;
    W2T[i3] = f2bf(w_ih[j * 256 + k]);
  }
  int i4 = idx - 458752;                   // cvec = b_i2s + b_s2s
  if (i4 >= 0 && i4 < 256) cvec[i4] = b_i2s[i4] + b_s2s[i4];
  int i5 = idx - 459008;                   // gbias[n] = b_ih[j] + b_hh[j]
  if (i5 >= 0 && i5 < 1024) {
    int chb = i5 >> 6, g = (i5 >> 4) & 3, cl = i5 & 15;
    int j = g * 256 + chb * 16 + cl;
    gbias[i5] = b_ih[j] + b_hh[j];
  }
}

// ---------------------------------------------------------------------------
// xs: banded masked 1x1 conv, computed once per (bb,i), reused for both
// directions (dir1 is j -> 63-j of the same conv). Output layout
// xs[dir][row][j][c] bf16 (c contiguous), j = t - i, in-band only.
// ---------------------------------------------------------------------------
__global__ __launch_bounds__(256) void xs_kernel(
    const float* __restrict__ x, const float* __restrict__ wm,
    unsigned short* __restrict__ xs) {
  extern __shared__ float xt[];                   // [256 cin][64 j]
  int blk = blockIdx.x;                           // bb*64 + i
  int bb = blk >> 6, ii = blk & 63;
  int tid = threadIdx.x;
  {
    const float4* src = (const float4*)(x + (((size_t)bb * 256 + tid) * 64 + ii) * 64);
    float4* dst = (float4*)(xt + tid * 64);
#pragma unroll
    for (int q = 0; q < 16; q++) dst[q] = src[q];
  }
  __syncthreads();

  int cp = tid & 127, c0 = cp * 2;
  int j0 = (tid >> 7) * 32;                       // wave-uniform (0 or 32)
  float acc0[32], acc1[32];
#pragma unroll
  for (int q = 0; q < 32; q++) { acc0[q] = 0.f; acc1[q] = 0.f; }

  for (int c4 = 0; c4 < 64; c4++) {
    float4 wa = *(const float4*)(wm + c0 * 256 + c4 * 4);
    float4 wb = *(const float4*)(wm + (c0 + 1) * 256 + c4 * 4);
    float wav[4] = {wa.x, wa.y, wa.z, wa.w};
    float wbv[4] = {wb.x, wb.y, wb.z, wb.w};
#pragma unroll
    for (int j4 = 0; j4 < 8; j4++) {
#pragma unroll
      for (int i = 0; i < 4; i++) {
        float4 xv = *(const float4*)(xt + (c4 * 4 + i) * 64 + j0 + j4 * 4);
        acc0[j4 * 4 + 0] = fmaf(wav[i], xv.x, acc0[j4 * 4 + 0]);
        acc0[j4 * 4 + 1] = fmaf(wav[i], xv.y, acc0[j4 * 4 + 1]);
        acc0[j4 * 4 + 2] = fmaf(wav[i], xv.z, acc0[j4 * 4 + 2]);
        acc0[j4 * 4 + 3] = fmaf(wav[i], xv.w, acc0[j4 * 4 + 3]);
        acc1[j4 * 4 + 0] = fmaf(wbv[i], xv.x, acc1[j4 * 4 + 0]);
        acc1[j4 * 4 + 1] = fmaf(wbv[i], xv.y, acc1[j4 * 4 + 1]);
        acc1[j4 * 4 + 2] = fmaf(wbv[i], xv.z, acc1[j4 * 4 + 2]);
        acc1[j4 * 4 + 3] = fmaf(wbv[i], xv.w, acc1[j4 * 4 + 3]);
      }
    }
  }
  size_t row = (size_t)blk;
#pragma unroll
  for (int q = 0; q < 32; q++) {
    int j = j0 + q;
    unsigned pv = (unsigned)f2bf(acc0[q]) | ((unsigned)f2bf(acc1[q]) << 16);
    *(unsigned*)(xs + ((row * 64 + j) * 256 + c0)) = pv;                      // dir0
    *(unsigned*)(xs + (16777216u + (row * 64 + (63 - j)) * 256 + c0)) = pv;   // dir1
  }
}

// ---------------------------------------------------------------------------
// phase A (per step): tmp[2048][256] = hs[t-1]@k0T + shift(hs[t-1])@k1T
//                                      + xs_t (banded) + cvec, stored bf16.
// 256 blocks: 32 M-tiles(64) x 8 N-tiles(32). 4 waves, wave tile 32x16.
// Frags loaded directly from L2-hot global (full 64B line use per wave load).
// ---------------------------------------------------------------------------
__global__ __launch_bounds__(256) void stepA_kernel(
    int t, const unsigned short* __restrict__ hs,
    const unsigned short* __restrict__ K01,
    const unsigned short* __restrict__ xs,
    const float* __restrict__ cvec, unsigned short* __restrict__ tmp) {
  int blk = blockIdx.x;
  int r0 = (blk >> 3) * 64, n0 = (blk & 7) * 32;
  int tid = threadIdx.x, lane = tid & 63, w = tid >> 6;
  int rbase = r0 + (w >> 1) * 32;
  int nb = n0 + (w & 1) * 16;
  int l15 = lane & 15, l4 = lane >> 4;

  f32x4 acc0 = {0.f, 0.f, 0.f, 0.f}, acc1 = {0.f, 0.f, 0.f, 0.f};
  if (t > 0) {
    const unsigned short* hprev = hs + (size_t)(t - 1) * RT_ * CC_;
    int R0 = rbase + l15, R1 = rbase + 16 + l15;
    bool m0 = ((R0 & 1023) == 1023), m1 = ((R1 & 1023) == 1023);
    const unsigned short* pa0 = hprev + R0 * 256;
    const unsigned short* pa1 = hprev + R1 * 256;
    const unsigned short* pb = K01 + (nb + l15) * 512;
    const s16x8 z = {0, 0, 0, 0, 0, 0, 0, 0};
#pragma unroll
    for (int ks = 0; ks < 8; ks++) {         // k0 part: h_prev
      int kk = ks * 32 + l4 * 8;
      s16x8 b = *(const s16x8*)(pb + kk);
      s16x8 a0 = *(const s16x8*)(pa0 + kk);
      s16x8 a1 = *(const s16x8*)(pa1 + kk);
      acc0 = __builtin_amdgcn_mfma_f32_16x16x32_bf16(a0, b, acc0, 0, 0, 0);
      acc1 = __builtin_amdgcn_mfma_f32_16x16x32_bf16(a1, b, acc1, 0, 0, 0);
    }
#pragma unroll
    for (int ks = 0; ks < 8; ks++) {         // k1 part: h_next (= row+1)
      int kk = ks * 32 + l4 * 8;
      s16x8 b = *(const s16x8*)(pb + 256 + kk);
      s16x8 a0 = m0 ? z : *(const s16x8*)(pa0 + 256 + kk);
      s16x8 a1 = m1 ? z : *(const s16x8*)(pa1 + 256 + kk);
      acc0 = __builtin_amdgcn_mfma_f32_16x16x32_bf16(a0, b, acc0, 0, 0, 0);
      acc1 = __builtin_amdgcn_mfma_f32_16x16x32_bf16(a1, b, acc1, 0, 0, 0);
    }
  }
  int Ccol = nb + l15;
  float cv = cvec[Ccol];
#pragma unroll
  for (int mi = 0; mi < 2; mi++) {
    f32x4 a = mi ? acc1 : acc0;
#pragma unroll
    for (int r = 0; r < 4; r++) {
      int R = rbase + mi * 16 + l4 * 4 + r;   // C/D: row=(lane>>4)*4+reg, col=lane&15
      float v = a[r] + cv;
      int rl = R & 1023, dir = R >> 10;
      int j = t - (rl & 63);
      if (j >= 0 && j < 64)
        v += bf2f(xs[(size_t)dir * 16777216u + ((size_t)rl * 64 + j) * 256 + Ccol]);
      tmp[R * 256 + Ccol] = f2bf(v);
    }
  }
}

// ---------------------------------------------------------------------------
// phase B (per step): gates = tmp @ w_ihT (gate-interleaved) + fused LSTM.
// 256 blocks: 32 M-tiles(64) x 8 N-tiles(128). Wave tile 32x64 spans all 4
// gates of 16 channels -> each lane holds i,f,g,o of one channel (no x-lane).
// ---------------------------------------------------------------------------
__global__ __launch_bounds__(256) void stepB_kernel(
    int t, const unsigned short* __restrict__ tmp,
    const unsigned short* __restrict__ W2T,
    const float* __restrict__ gbias, float* __restrict__ cstate,
    unsigned short* __restrict__ hs) {
  int blk = blockIdx.x;
  int r0 = (blk >> 3) * 64, n0 = (blk & 7) * 128;
  int tid = threadIdx.x, lane = tid & 63, w = tid >> 6;
  int rbase = r0 + (w >> 1) * 32;
  int nbase = n0 + (w & 1) * 64;
  int l15 = lane & 15, l4 = lane >> 4;

  f32x4 acc[2][4];
#pragma unroll
  for (int a = 0; a < 2; a++)
#pragma unroll
    for (int b = 0; b < 4; b++) acc[a][b] = (f32x4){0.f, 0.f, 0.f, 0.f};

  const unsigned short* pa0 = tmp + (rbase + l15) * 256;
  const unsigned short* pa1 = tmp + (rbase + 16 + l15) * 256;
  const unsigned short* pb0 = W2T + (nbase + l15) * 256;
#pragma unroll
  for (int ks = 0; ks < 8; ks++) {
    int kk = ks * 32 + l4 * 8;
    s16x8 a0 = *(const s16x8*)(pa0 + kk);
    s16x8 a1 = *(const s16x8*)(pa1 + kk);
#pragma unroll
    for (int ni = 0; ni < 4; ni++) {
      s16x8 b = *(const s16x8*)(pb0 + ni * 16 * 256 + kk);
      acc[0][ni] = __builtin_amdgcn_mfma_f32_16x16x32_bf16(a0, b, acc[0][ni], 0, 0, 0);
      acc[1][ni] = __builtin_amdgcn_mfma_f32_16x16x32_bf16(a1, b, acc[1][ni], 0, 0, 0);
    }
  }
  int cl = l15;
  int ch = (nbase >> 2) + cl;                  // chb*16 + cl
  float gb0 = gbias[nbase + cl];
  float gb1 = gbias[nbase + 16 + cl];
  float gb2 = gbias[nbase + 32 + cl];
  float gb3 = gbias[nbase + 48 + cl];
  unsigned short* hout = hs + (size_t)t * RT_ * CC_;
#pragma unroll
  for (int mi = 0; mi < 2; mi++) {
#pragma unroll
    for (int r = 0; r < 4; r++) {
      int R = rbase + mi * 16 + l4 * 4 + r;
      float xi = acc[mi][0][r] + gb0;
      float xf = acc[mi][1][r] + gb1;
      float xg = acc[mi][2][r] + gb2;
      float xo = acc[mi][3][r] + gb3;
      float si = 1.f / (1.f + __expf(-xi));
      float sf = 1.f / (1.f + __expf(-xf));
      float so = 1.f / (1.f + __expf(-xo));
      float tg = 1.f - 2.f / (__expf(2.f * xg) + 1.f);
      float cold = (t == 0) ? 0.f : cstate[R * 256 + ch];
      float cn = sf * cold + si * tg;
      cstate[R * 256 + ch] = cn;
      float th = 1.f - 2.f / (__expf(2.f * cn) + 1.f);
      hout[R * 256 + ch] = f2bf(so * th);
    }
  }
}

// ---------------------------------------------------------------------------
// gather: out[b,o,hh,j] = hs0[hh+j][row][c0+hh] + (hh>0)*hs1[hh-1+63-j][row][c0+hh-1]
// row = b*64 + (o>>2), c0 = (o&3)*64. Slabs staged in LDS (pitch 66).
// ---------------------------------------------------------------------------
__global__ __launch_bounds__(256) void gather_kernel(
    const unsigned short* __restrict__ hs, float* __restrict__ out) {
  __shared__ unsigned short slab0[127 * 66 + 2];
  __shared__ unsigned short slab1[127 * 66 + 2];
  int blk = blockIdx.x;                    // bb*256 + o
  int bb = blk >> 8, o = blk & 255;
  int row = bb * 64 + (o >> 2);
  int c0 = (o & 3) * 64;
  int tid = threadIdx.x;
  for (int idx = tid; idx < 127 * 32; idx += 256) {
    int tt = idx >> 5, cu = idx & 31;
    unsigned v0 = *(const unsigned*)(hs + ((size_t)tt * RT_ + row) * 256 + c0 + cu * 2);
    unsigned v1 = *(const unsigned*)(hs + ((size_t)tt * RT_ + 1024 + row) * 256 + c0 + cu * 2);
    *(unsigned*)(slab0 + tt * 66 + cu * 2) = v0;
    *(unsigned*)(slab1 + tt * 66 + cu * 2) = v1;
  }
  __syncthreads();
  int j = tid & 63;
  int hh0 = (tid >> 6) * 16;
  float* ob = out + (size_t)blk * 4096;
  for (int hh = hh0; hh < hh0 + 16; hh++) {
    float v = bf2f(slab0[(hh + j) * 66 + hh]);
    if (hh > 0) v += bf2f(slab1[(hh - 1 + 63 - j) * 66 + (hh - 1)]);
    ob[hh * 64 + j] = v;
  }
}

// ---------------------------------------------------------------------------
extern "C" void kernel_launch(void* const* d_in, const int* in_sizes, int n_in,
                              void* d_out, int out_size, void* d_ws, size_t ws_size,
                              hipStream_t stream) {
  const float* x     = (const float*)d_in[0];
  const float* w_i2s = (const float*)d_in[1];
  const float* b_i2s = (const float*)d_in[2];
  const float* w_ih  = (const float*)d_in[3];
  const float* b_ih  = (const float*)d_in[4];
  const float* b_hh  = (const float*)d_in[5];
  const float* k0    = (const float*)d_in[6];
  const float* k1    = (const float*)d_in[7];
  const float* b_s2s = (const float*)d_in[8];
  float* out = (float*)d_out;

  char* ws = (char*)d_ws;
  // workspace map (bytes)
  float*          wm     = (float*)(ws + 0);                 //   256 KiB
  float*          cvec   = (float*)(ws + 262144);            //     1 KiB
  float*          gbias  = (float*)(ws + 263168);            //     4 KiB
  unsigned short* K01    = (unsigned short*)(ws + 267264);   //   256 KiB
  unsigned short* W2T    = (unsigned short*)(ws + 529408);   //   512 KiB
  unsigned short* tmp    = (unsigned short*)(ws + 1053696);  //     1 MiB
  float*          cstate = (float*)(ws + 2102272);           //     2 MiB
  unsigned short* xs     = (unsigned short*)(ws + 4199424);  //    64 MiB
  unsigned short* hs     = (unsigned short*)(ws + 71308288); //   127 MiB
  const size_t NEEDED = 204477440;
  if (ws_size < NEEDED) return;  // workspace too small; fail loudly via mismatch

  prep_kernel<<<1797, 256, 0, stream>>>(w_i2s, b_i2s, w_ih, b_ih, b_hh, k0, k1,
                                        b_s2s, wm, K01, W2T, cvec, gbias);
  xs_kernel<<<1024, 256, 65536, stream>>>(x, wm, xs);
  for (int t = 0; t < 127; t++) {
    stepA_kernel<<<256, 256, 0, stream>>>(t, hs, K01, xs, cvec, tmp);
    stepB_kernel<<<256, 256, 0, stream>>>(t, tmp, W2T, gbias, cstate, hs);
  }
  gather_kernel<<<4096, 256, 0, stream>>>(hs, out);
}